// Round 8
// baseline (2871.812 us; speedup 1.0000x reference)
//
#include <hip/hip_runtime.h>
#include <hip/hip_bf16.h>

#define Bdim 64
#define Sdim 2048
#define Hdim 256

typedef __attribute__((ext_vector_type(8))) short short8;
typedef __attribute__((ext_vector_type(4))) float f32x4;

static __device__ __forceinline__ unsigned short f2bf(float f) {
  union { float f; unsigned int u; } v; v.f = f;
  unsigned int r = v.u + 0x7fffu + ((v.u >> 16) & 1u);  // RNE
  return (unsigned short)(r >> 16);
}
static __device__ __forceinline__ float bf2f(unsigned short u) {
  union { unsigned int u; float f; } v; v.u = ((unsigned int)u) << 16;
  return v.f;
}
static __device__ __forceinline__ float bflo(unsigned int u) {
  union { unsigned int u; float f; } v; v.u = u << 16; return v.f;
}
static __device__ __forceinline__ float bfhi(unsigned int u) {
  union { unsigned int u; float f; } v; v.u = u & 0xffff0000u; return v.f;
}

#if __has_builtin(__builtin_amdgcn_rcpf)
#define FAST_RCP(x) __builtin_amdgcn_rcpf(x)
#else
#define FAST_RCP(x) (1.0f / (x))
#endif

// tanh(x) = 1 - 2/(1 + e^{2x}) : 5 ops, saturates correctly at +/-inf.
static __device__ __forceinline__ float tanh_fast(float x) {
  float e = exp2f(x * 2.8853900817779268f);  // e^{2x}
  return 1.0f - 2.0f * FAST_RCP(1.0f + e);
}

#define STEP_BAR() do { __builtin_amdgcn_sched_barrier(0); \
    asm volatile("s_waitcnt lgkmcnt(0)" ::: "memory"); \
    __builtin_amdgcn_s_barrier(); \
    __builtin_amdgcn_sched_barrier(0); } while (0)

// ---------------------------------------------------------------------------
// Phase 2: sequential scan, MFMA transposed (D = W_hh . h^T), 4 waves,
// ZERO global ops in the steady-state loop.
// 4 blocks x 256 threads; block = 16 batches; wave wv owns n-cols wv*64..+63.
// LDS (64 KiB): hist = 4 rotating h slots (8 KiB each, bf16, XOR-swizzled);
// xwb = one 4-step xw chunk tile [ts][batch][512B swz].
// Chunked pipeline (4 steps/chunk): boundary does {ds_write staged xw chunk C;
// flush h of chunk C-1 to ws2 (coalesced bf16); issue coalesced reg-prefetch
// of chunk C+1}; steps touch only LDS/regs/MFMA. Per-step barrier = lgkm-only.
// All fragment packings / swizzles / D-layout identical to r7 (device-verified).
// ---------------------------------------------------------------------------
__global__ __launch_bounds__(256, 1) void rnn_scan_mfma(
    const unsigned short* __restrict__ xw1,   // bf16 xw [B][S][H]
    const float* __restrict__ Whh,
    unsigned short* __restrict__ ws2,         // bf16 h history [B][S][H]
    float* __restrict__ hfin) {
  __shared__ __align__(16) char lds[65536];   // [0,32K)=hist(4x8K), [32K,64K)=xwb
  const int tid = threadIdx.x;
  const int lane = tid & 63;
  const int wv = tid >> 6;     // wave 0..3 -> n-cols wv*64..+63
  const int l15 = lane & 15;   // batch selector (D col) and W-row selector
  const int g = lane >> 4;     // 0..3
  const int bs = blockIdx.x * 16;

  // A-frags (W_hh): lane (l15,g) holds W_hh[n][k], n = wv*64+tau*16+l15,
  // k = ks*32+g*8+e  (device-verified packing).
  short8 wfrag[4][8];
#pragma unroll
  for (int tau = 0; tau < 4; ++tau) {
    int n = wv * 64 + tau * 16 + l15;
#pragma unroll
    for (int ks = 0; ks < 8; ++ks) {
      int k0 = ks * 32 + g * 8;
      const float* p = Whh + n * 256 + k0;
      short8 v;
#pragma unroll
      for (int e = 0; e < 8; ++e) v[e] = (short)f2bf(p[e]);
      wfrag[tau][ks] = v;
    }
  }

  // B-frag (h) LDS byte offsets within a hist slot (device-verified swizzle)
  int aroff[8];
#pragma unroll
  for (int ks = 0; ks < 8; ++ks)
    aroff[ks] = l15 * 512 + ((ks * 64 + g * 16) ^ ((l15 & 7) << 4));

  // Per-thread outputs: batch = bs+l15, n = wv*64 + tau*16 + g*4 + e
  int nb[4], wo[4], xo[4];
#pragma unroll
  for (int tau = 0; tau < 4; ++tau) {
    nb[tau] = wv * 64 + tau * 16 + g * 4;
    wo[tau] = l15 * 512 + ((2 * nb[tau]) ^ ((l15 & 7) << 4));          // h write
    xo[tau] = 32768 + l15 * 512 + ((2 * nb[tau]) ^ ((l15 & 7) << 4)); // xw read
  }

  // zero hist (h0 = 0 read from slot 3 at t=0)
  {
    uint4 z; z.x = z.y = z.z = z.w = 0;
#pragma unroll
    for (int i = 0; i < 8; ++i) *((uint4*)lds + i * 256 + tid) = z;
  }

  // chunk-id decomposition for stage/flush: c = [m(4b)][ts(2b)][n8(5b)]
  const int c_n8 = tid & 31, c_ts = (tid >> 5) & 3, c_m0 = tid >> 7;  // +2*it on m
  uint4 stg[8];

  // prologue: prefetch chunk 0 into regs
#pragma unroll
  for (int it = 0; it < 8; ++it) {
    int m = c_m0 + it * 2;
    long e = ((long)(bs + m) * Sdim + c_ts) * Hdim + c_n8 * 8;
    stg[it] = *(const uint4*)(xw1 + e);
  }

  for (int C = 0; C < 512; ++C) {
    // [B] write staged xw chunk C into xwb (compiler inserts counted vmcnt)
#pragma unroll
    for (int it = 0; it < 8; ++it) {
      int m = c_m0 + it * 2;
      *(uint4*)(lds + 32768 + c_ts * 8192 + m * 512 + ((c_n8 * 16) ^ ((m & 7) << 4))) = stg[it];
    }
    // [C2] flush h history of chunk C-1 (coalesced bf16 stores)
    if (C > 0) {
      const int t0p = (C - 1) * 4;
#pragma unroll
      for (int it = 0; it < 8; ++it) {
        int m = c_m0 + it * 2;
        uint4 v = *(const uint4*)(lds + c_ts * 8192 + m * 512 + ((c_n8 * 16) ^ ((m & 7) << 4)));
        long e = ((long)(bs + m) * Sdim + (t0p + c_ts)) * Hdim + c_n8 * 8;
        *(uint4*)(ws2 + e) = v;
      }
    }
    // [D] issue reg-prefetch of chunk C+1 (pinned before the barrier below)
    if (C < 511) {
      const long t0n = (long)(C + 1) * 4;
#pragma unroll
      for (int it = 0; it < 8; ++it) {
        int m = c_m0 + it * 2;
        long e = ((long)(bs + m) * Sdim + (t0n + c_ts)) * Hdim + c_n8 * 8;
        stg[it] = *(const uint4*)(xw1 + e);
      }
    }
    // [E] boundary barrier
    STEP_BAR();

    // [F] 4 steps; ts compile-time -> all LDS offsets are literals
#pragma unroll
    for (int ts = 0; ts < 4; ++ts) {
      const int rs = (ts + 3) & 3;   // read slot  (h[t-1])
      const int t = C * 4 + ts;

      f32x4 acc[4];
#pragma unroll
      for (int tau = 0; tau < 4; ++tau) {       // acc init = xw_t (bf16 unpack)
        uint2 q = *(const uint2*)(lds + ts * 8192 + xo[tau]);
        acc[tau][0] = bflo(q.x); acc[tau][1] = bfhi(q.x);
        acc[tau][2] = bflo(q.y); acc[tau][3] = bfhi(q.y);
      }

#pragma unroll
      for (int ks = 0; ks < 8; ++ks) {
        short8 h8 = *(const short8*)(lds + rs * 8192 + aroff[ks]);
#pragma unroll
        for (int tau = 0; tau < 4; ++tau)
          acc[tau] = __builtin_amdgcn_mfma_f32_16x16x32_bf16(wfrag[tau][ks], h8, acc[tau], 0, 0, 0);
      }

#pragma unroll
      for (int tau = 0; tau < 4; ++tau) {
        f32x4 v;
#pragma unroll
        for (int e = 0; e < 4; ++e) v[e] = tanh_fast(acc[tau][e]);
        unsigned int plo, phi;
        asm("v_cvt_pk_bf16_f32 %0, %1, %2" : "=v"(plo) : "v"(v[0]), "v"(v[1]));
        asm("v_cvt_pk_bf16_f32 %0, %1, %2" : "=v"(phi) : "v"(v[2]), "v"(v[3]));
        *(uint2*)(lds + ts * 8192 + wo[tau]) = make_uint2(plo, phi);  // h[t] -> slot ts
        if (t == Sdim - 1)
          *(f32x4*)(hfin + (bs + l15) * Hdim + nb[tau]) = v;          // one-time
      }
      STEP_BAR();
    }
  }

  // final flush: chunk 511 (h[2044..2047])
  {
    const int t0p = 511 * 4;
#pragma unroll
    for (int it = 0; it < 8; ++it) {
      int m = c_m0 + it * 2;
      uint4 v = *(const uint4*)(lds + c_ts * 8192 + m * 512 + ((c_n8 * 16) ^ ((m & 7) << 4)));
      long e = ((long)(bs + m) * Sdim + (t0p + c_ts)) * Hdim + c_n8 * 8;
      *(uint4*)(ws2 + e) = v;
    }
  }
}

// ---------------------------------------------------------------------------
// Fallback scan (tiny workspace): fused VALU version — known-good from round 3.
// ---------------------------------------------------------------------------
__global__ __launch_bounds__(256, 1) void rnn_scan_valu_fused(
    const float* __restrict__ x, const float* __restrict__ Wih,
    const float* __restrict__ bh, const float* __restrict__ Whh,
    float* __restrict__ hout, float* __restrict__ hfin) {
  __shared__ __align__(16) uint2 wt[64][256];
  __shared__ __align__(16) float hl[256];
  const int n = threadIdx.x;
  const int b = blockIdx.x;
  {
    const float2* src = (const float2*)Whh;
    unsigned int* w32 = (unsigned int*)wt;
    for (int i = n; i < 32768; i += 256) {
      float2 f = src[i];
      unsigned int u = (unsigned int)f2bf(f.x) | ((unsigned int)f2bf(f.y) << 16);
      int row = i >> 7, kk = i & 127, k4 = kk >> 1, half = kk & 1;
      w32[k4 * 512 + row * 2 + half] = u;
    }
  }
  hl[n] = 0.0f;
  __syncthreads();
  const long base = (long)b * Sdim * Hdim + n;
  for (int t = 0; t < Sdim; ++t) {
    const float* xr = x + ((long)b * Sdim + t) * 256;
    const float* wr = Wih + n * 256;
    float acc = bh[n];
    for (int k = 0; k < 256; ++k) acc += xr[k] * wr[k];
#pragma unroll 8
    for (int k4 = 0; k4 < 64; ++k4) {
      uint2 w2 = wt[k4][n];
      float4 h4 = *(const float4*)&hl[k4 * 4];
      acc += bflo(w2.x) * h4.x + bfhi(w2.x) * h4.y
           + bflo(w2.y) * h4.z + bfhi(w2.y) * h4.w;
    }
    float hv = tanh_fast(acc);
    __syncthreads();
    hl[n] = hv;
    hout[base + (long)t * Hdim] = hv;
    if (t == Sdim - 1) hfin[b * Hdim + n] = hv;
    __syncthreads();
  }
}

// ---------------------------------------------------------------------------
// Phases 1 & 3: out[r,n] = A[r,:] @ W[n,:] + bias[n], A is [131072,256].
// 512 thr (8 waves), 128 rows/block; W fully staged in STATIC LDS (bf16,
// XOR-swizzled). A_F32: fp32 vs bf16 A; OUT_F32: fp32 vs bf16 out.
// ---------------------------------------------------------------------------
template<int A_F32, int OUT_F32>
__global__ __launch_bounds__(512, 2) void gemm256(const void* __restrict__ Ap,
                                                  const float* __restrict__ Wf,
                                                  const float* __restrict__ bias,
                                                  void* __restrict__ outp) {
  __shared__ __align__(16) char wl[131072];
  const int tid = threadIdx.x;
  const int lane = tid & 63;
  const int wv = tid >> 6;
  const int l15 = lane & 15;
  const int g = lane >> 4;
  const long r0 = (long)blockIdx.x * 128;

  for (int i = tid; i < 256 * 64; i += 512) {
    int n = i >> 6;
    int kc = (i & 63) * 4;
    f32x4 c = *(const f32x4*)(Wf + n * 256 + kc);
    unsigned int lo = (unsigned int)f2bf(c[0]) | ((unsigned int)f2bf(c[1]) << 16);
    unsigned int hi = (unsigned int)f2bf(c[2]) | ((unsigned int)f2bf(c[3]) << 16);
    int kb = (kc * 2) ^ ((n & 7) << 4);
    unsigned int* dst = (unsigned int*)(wl + n * 512 + kb);
    dst[0] = lo; dst[1] = hi;
  }
  __syncthreads();

  f32x4 acc[16];
#pragma unroll
  for (int tau = 0; tau < 16; ++tau) {
    float bv = bias[tau * 16 + l15];
    acc[tau][0] = bv; acc[tau][1] = bv; acc[tau][2] = bv; acc[tau][3] = bv;
  }

  const long arow = r0 + wv * 16 + l15;
#pragma unroll
  for (int ks = 0; ks < 8; ++ks) {
    const int k0 = ks * 32 + g * 8;
    short8 a;
    if (A_F32) {
      const f32x4* ap = (const f32x4*)((const float*)Ap + arow * 256 + k0);
      f32x4 x0 = ap[0], x1 = ap[1];
#pragma unroll
      for (int e = 0; e < 4; ++e) { a[e] = (short)f2bf(x0[e]); a[4 + e] = (short)f2bf(x1[e]); }
    } else {
      a = *(const short8*)((const unsigned short*)Ap + arow * 256 + k0);
    }
#pragma unroll
    for (int tau = 0; tau < 16; ++tau) {
      int n = tau * 16 + l15;
      int kb = (k0 * 2) ^ ((n & 7) << 4);
      short8 b = *(const short8*)(wl + n * 512 + kb);
      acc[tau] = __builtin_amdgcn_mfma_f32_16x16x32_bf16(a, b, acc[tau], 0, 0, 0);
    }
  }

#pragma unroll
  for (int tau = 0; tau < 16; ++tau) {
    int n = tau * 16 + l15;
#pragma unroll
    for (int e = 0; e < 4; ++e) {
      long row = r0 + wv * 16 + g * 4 + e;
      if (OUT_F32) ((float*)outp)[row * 256 + n] = acc[tau][e];
      else         ((unsigned short*)outp)[row * 256 + n] = f2bf(acc[tau][e]);
    }
  }
}

extern "C" void kernel_launch(void* const* d_in, const int* in_sizes, int n_in,
                              void* d_out, int out_size, void* d_ws, size_t ws_size,
                              hipStream_t stream) {
  const float* x    = (const float*)d_in[0];
  const float* W_ih = (const float*)d_in[1];
  const float* W_hh = (const float*)d_in[2];
  const float* b_h  = (const float*)d_in[3];
  const float* W_ho = (const float*)d_in[4];
  const float* b_o  = (const float*)d_in[5];
  float* out  = (float*)d_out;
  float* hfin = out + (size_t)Bdim * Sdim * Hdim;

  const int gblocks = (Bdim * Sdim) / 128;                    // 1024
  const size_t half = (size_t)Bdim * Sdim * Hdim * 2;         // 64 MiB (bf16 plane)

  if (ws_size >= 2 * half) {
    unsigned short* ws1 = (unsigned short*)d_ws;              // bf16 xw
    unsigned short* ws2 = ws1 + (size_t)Bdim * Sdim * Hdim;   // bf16 h history
    gemm256<1, 0><<<gblocks, 512, 0, stream>>>(x, W_ih, b_h, ws1);   // phase 1
    rnn_scan_mfma<<<4, 256, 0, stream>>>(ws1, W_hh, ws2, hfin);      // phase 2
    gemm256<0, 1><<<gblocks, 512, 0, stream>>>(ws2, W_ho, b_o, out); // phase 3
  } else {
    rnn_scan_valu_fused<<<Bdim, 256, 0, stream>>>(x, W_ih, b_h, W_hh, out, hfin);
    gemm256<1, 1><<<gblocks, 512, 0, stream>>>(out, W_ho, b_o, out); // in place
  }
}